// Round 2
// baseline (168.009 us; speedup 1.0000x reference)
//
#include <hip/hip_runtime.h>
#include <math.h>

#define N_V 100000
#define N_J 24
#define N_BETAS 300
#define N_POSE 207
#define JSPLIT 8
#define VERT_BLOCKS 2048
#define N_WAVES (VERT_BLOCKS * 4)

__constant__ int c_parents[N_J] = {0,0,0,0,1,2,3,4,5,6,7,8,9,9,9,12,13,14,16,17,18,19,20,21};

// ---------------- K1: rodrigues + lrotmin ----------------
__global__ void k_rodrigues(const float* __restrict__ pose,
                            float* __restrict__ ws_R,
                            float* __restrict__ ws_lrot) {
    __shared__ float Rsh[N_J][9];
    int t = threadIdx.x;
    if (t < N_J) {
        float x = pose[t*3+0], y = pose[t*3+1], z = pose[t*3+2];
        float th = sqrtf(x*x + y*y + z*z + 1e-16f);
        float inv = 1.0f / th;
        float rx = x*inv, ry = y*inv, rz = z*inv;
        float c = cosf(th), s = sinf(th), o = 1.0f - c;
        float R[9];
        R[0] = c + o*rx*rx;      R[1] = o*rx*ry - s*rz;  R[2] = o*rx*rz + s*ry;
        R[3] = o*ry*rx + s*rz;   R[4] = c + o*ry*ry;     R[5] = o*ry*rz - s*rx;
        R[6] = o*rz*rx - s*ry;   R[7] = o*rz*ry + s*rx;  R[8] = c + o*rz*rz;
        #pragma unroll
        for (int i = 0; i < 9; ++i) { Rsh[t][i] = R[i]; ws_R[t*9+i] = R[i]; }
    }
    __syncthreads();
    for (int i = t; i < N_POSE; i += blockDim.x) {
        int j = i / 9 + 1, e = i % 9;
        float v = Rsh[j][e];
        if (e == 0 || e == 4 || e == 8) v -= 1.0f;
        ws_lrot[i] = v;
    }
}

// ---------------- K2: grid-stride wave-per-vertex, register operands -------
// vs / vp are SoA: [3][N_V]
__global__ __launch_bounds__(256) void k_vertex(
        const float* __restrict__ shapedirs, const float* __restrict__ posedirs,
        const float* __restrict__ v_template, const float* __restrict__ beta,
        const float* __restrict__ lrot,
        float* __restrict__ vs, float* __restrict__ vp) {
    int lane = threadIdx.x & 63;
    int wid  = (blockIdx.x * 256 + threadIdx.x) >> 6;   // global wave id

    // ---- per-wave invariant operands -> registers (L1-cached global reads)
    float4 bv[4];
    #pragma unroll
    for (int it = 0; it < 4; ++it) {
        int i = lane + it * 64;                 // float4 index within 225
        int d = (i >= 150) ? 2 : ((i >= 75) ? 1 : 0);
        int k4 = i - d * 75;
        if (it < 3 || i < 225) bv[it] = ((const float4*)beta)[k4];
        else                   bv[it] = make_float4(0.f, 0.f, 0.f, 0.f);
    }
    float lr[10];
    #pragma unroll
    for (int it = 0; it < 10; ++it) {
        int i = lane + it * 64;                 // float index within 621
        int d = (i >= 414) ? 2 : ((i >= 207) ? 1 : 0);
        int p = i - d * 207;
        lr[it] = (it < 9 || i < 621) ? lrot[p] : 0.f;
    }

    for (int v = wid; v < N_V; v += N_WAVES) {
        const float4* sb = (const float4*)(shapedirs + (size_t)v * 900);
        const float*  pb = posedirs + (size_t)v * 621;

        float a0 = 0.f, a1 = 0.f, a2 = 0.f;    // shapedirs dot per dim
        float p0 = 0.f, p1 = 0.f, p2 = 0.f;    // posedirs dot per dim

        // ---- shapedirs: 225 float4 (segment boundaries at f4 75 / 150)
        {
            float4 s0 = sb[lane];
            float4 s1 = sb[lane + 64];
            float4 s2 = sb[lane + 128];
            float c0 = s0.x*bv[0].x + s0.y*bv[0].y + s0.z*bv[0].z + s0.w*bv[0].w;
            float c1 = s1.x*bv[1].x + s1.y*bv[1].y + s1.z*bv[1].z + s1.w*bv[1].w;
            float c2 = s2.x*bv[2].x + s2.y*bv[2].y + s2.z*bv[2].z + s2.w*bv[2].w;
            a0 += c0;
            if (lane < 11) a0 += c1; else a1 += c1;     // it1 straddles 75
            if (lane < 22) a1 += c2; else a2 += c2;     // it2 straddles 150
            if (lane < 33) {                            // it3 tail, all d2
                float4 s3 = sb[lane + 192];
                a2 += s3.x*bv[3].x + s3.y*bv[3].y + s3.z*bv[3].z + s3.w*bv[3].w;
            }
        }
        // ---- posedirs: 621 scalars (boundaries at 207 / 414 / 621)
        {
            float c;
            p0 += pb[lane      ] * lr[0];
            p0 += pb[lane +  64] * lr[1];
            p0 += pb[lane + 128] * lr[2];
            c = pb[lane + 192] * lr[3];
            if (lane < 15) p0 += c; else p1 += c;       // straddles 207
            p1 += pb[lane + 256] * lr[4];
            p1 += pb[lane + 320] * lr[5];
            c = pb[lane + 384] * lr[6];
            if (lane < 30) p1 += c; else p2 += c;       // straddles 414
            p2 += pb[lane + 448] * lr[7];
            p2 += pb[lane + 512] * lr[8];
            if (lane < 45) p2 += pb[lane + 576] * lr[9];// tail (OOB guard)
        }

        // ---- 6-value cross-lane reduction: 18 + 3 + 1 ds ops
        #pragma unroll
        for (int off = 1; off <= 4; off <<= 1) {
            a0 += __shfl_xor(a0, off); a1 += __shfl_xor(a1, off); a2 += __shfl_xor(a2, off);
            p0 += __shfl_xor(p0, off); p1 += __shfl_xor(p1, off); p2 += __shfl_xor(p2, off);
        }
        int j = lane & 7;
        float val = a0;
        val = (j == 1) ? a1 : val;
        val = (j == 2) ? a2 : val;
        val = (j == 3) ? p0 : val;
        val = (j == 4) ? p1 : val;
        val = (j == 5) ? p2 : val;
        val += __shfl_xor(val, 8);
        val += __shfl_xor(val, 16);
        val += __shfl_xor(val, 32);
        float pj = __shfl(val, lane + 3);   // lane d<3 pulls pose-sum d

        if (lane < 3) {
            float vsd = val + v_template[(size_t)v*3 + lane];
            vs[lane * N_V + v] = vsd;
            vp[lane * N_V + v] = vsd + pj;
        }
    }
}

// ---------------- K3: J partials (float4 over SoA v_shaped) ----------------
__global__ __launch_bounds__(256) void k_jreg(const float* __restrict__ Jr,
                                              const float* __restrict__ vs,
                                              float* __restrict__ jpart) {
    int j = blockIdx.x / JSPLIT;
    int s = blockIdx.x % JSPLIT;
    const int chunk4 = (N_V / JSPLIT) / 4;   // 3125 float4
    int b4 = s * chunk4;
    int t = threadIdx.x;
    const float4* row = (const float4*)(Jr + (size_t)j * N_V);
    const float4* X = (const float4*)(vs);
    const float4* Y = (const float4*)(vs + N_V);
    const float4* Z = (const float4*)(vs + 2 * N_V);
    float a0 = 0.f, a1 = 0.f, a2 = 0.f;
    for (int i = b4 + t; i < b4 + chunk4; i += 256) {
        float4 w = row[i];
        float4 x = X[i], y = Y[i], z = Z[i];
        a0 += w.x*x.x + w.y*x.y + w.z*x.z + w.w*x.w;
        a1 += w.x*y.x + w.y*y.y + w.z*y.z + w.w*y.w;
        a2 += w.x*z.x + w.y*z.y + w.z*z.z + w.w*z.w;
    }
    #pragma unroll
    for (int off = 32; off; off >>= 1) {
        a0 += __shfl_xor(a0, off); a1 += __shfl_xor(a1, off); a2 += __shfl_xor(a2, off);
    }
    __shared__ float red[4][3];
    int wave = t >> 6, lane = t & 63;
    if (lane == 0) { red[wave][0] = a0; red[wave][1] = a1; red[wave][2] = a2; }
    __syncthreads();
    if (t == 0) {
        jpart[(j*JSPLIT+s)*3+0] = red[0][0]+red[1][0]+red[2][0]+red[3][0];
        jpart[(j*JSPLIT+s)*3+1] = red[0][1]+red[1][1]+red[2][1]+red[3][1];
        jpart[(j*JSPLIT+s)*3+2] = red[0][2]+red[1][2]+red[2][2]+red[3][2];
    }
}

// ---------------- K4: reduce J + kinematic chain -> G' [24][12] ------------
__global__ void k_chain(const float* __restrict__ jpart,
                        const float* __restrict__ ws_R,
                        float* __restrict__ ws_G) {
    __shared__ float J[N_J][3];
    __shared__ float G[N_J][16];
    int t = threadIdx.x;   // 64 threads
    for (int i = t; i < N_J * 3; i += 64) {
        int j = i / 3, d = i % 3;
        float s = 0.f;
        #pragma unroll
        for (int k = 0; k < JSPLIT; ++k) s += jpart[(j*JSPLIT+k)*3 + d];
        J[j][d] = s;
    }
    __syncthreads();
    if (t < 16) {
        int a = t / 4, b = t % 4;
        float g;
        if (a < 3) g = (b < 3) ? ws_R[a*3 + b] : J[0][a];
        else       g = (b == 3) ? 1.f : 0.f;
        G[0][t] = g;
    }
    __syncthreads();
    for (int i = 1; i < N_J; ++i) {
        int p = c_parents[i];
        if (t < 16) {
            int a = t / 4, b = t % 4;
            float acc = 0.f;
            #pragma unroll
            for (int k = 0; k < 4; ++k) {
                float Ak;
                if (k < 3) Ak = (b < 3) ? ws_R[i*9 + k*3 + b] : (J[i][k] - J[p][k]);
                else       Ak = (b == 3) ? 1.f : 0.f;
                acc += G[p][a*4 + k] * Ak;
            }
            G[i][t] = acc;
        }
        __syncthreads();
    }
    for (int i = t; i < N_J * 12; i += 64) {
        int j = i / 12, r = i % 12, a = r / 4, b = r % 4;
        float g = G[j][a*4 + b];
        if (b == 3)
            g -= G[j][a*4+0]*J[j][0] + G[j][a*4+1]*J[j][1] + G[j][a*4+2]*J[j][2];
        ws_G[i] = g;
    }
}

// ---------------- K5: skinning (SoA v_posed) --------------------------------
__global__ __launch_bounds__(256) void k_skin(const float* __restrict__ w,
                                              const float* __restrict__ ws_G,
                                              const float* __restrict__ vp,
                                              float* __restrict__ out) {
    __shared__ float G[N_J * 12];
    int t = threadIdx.x;
    for (int i = t; i < N_J * 12; i += 256) G[i] = ws_G[i];
    __syncthreads();
    int v = blockIdx.x * 256 + t;
    if (v >= N_V) return;
    float T[12];
    #pragma unroll
    for (int r = 0; r < 12; ++r) T[r] = 0.f;
    const float4* wv = (const float4*)(w + (size_t)v * 24);
    #pragma unroll
    for (int q = 0; q < 6; ++q) {
        float4 ww = wv[q];
        float wj[4] = {ww.x, ww.y, ww.z, ww.w};
        #pragma unroll
        for (int jj = 0; jj < 4; ++jj) {
            const float* g = &G[(q*4 + jj) * 12];
            #pragma unroll
            for (int r = 0; r < 12; ++r) T[r] += wj[jj] * g[r];
        }
    }
    float px = vp[v], py = vp[N_V + v], pz = vp[2*N_V + v];
    out[v*3+0] = T[0]*px + T[1]*py + T[2]*pz  + T[3];
    out[v*3+1] = T[4]*px + T[5]*py + T[6]*pz  + T[7];
    out[v*3+2] = T[8]*px + T[9]*py + T[10]*pz + T[11];
}

// ---------------- launcher --------------------------------------------------
extern "C" void kernel_launch(void* const* d_in, const int* in_sizes, int n_in,
                              void* d_out, int out_size, void* d_ws, size_t ws_size,
                              hipStream_t stream) {
    const float* beta       = (const float*)d_in[0];
    const float* pose       = (const float*)d_in[1];
    const float* v_template = (const float*)d_in[2];
    const float* Jr         = (const float*)d_in[3];
    const float* skin_w     = (const float*)d_in[4];
    const float* shapedirs  = (const float*)d_in[5];
    const float* posedirs   = (const float*)d_in[6];
    float* out = (float*)d_out;

    float* ws      = (float*)d_ws;
    float* ws_R    = ws;              // 216
    float* ws_lrot = ws + 256;        // 207
    float* ws_vs   = ws + 512;        // 3*N_V  (SoA)
    float* ws_vp   = ws + 512 + 3*N_V;// 3*N_V  (SoA)
    float* ws_jp   = ws + 512 + 6*N_V;        // 576
    float* ws_G    = ws + 512 + 6*N_V + 640;  // 288

    k_rodrigues<<<1, 256, 0, stream>>>(pose, ws_R, ws_lrot);
    k_vertex<<<VERT_BLOCKS, 256, 0, stream>>>(shapedirs, posedirs, v_template,
                                              beta, ws_lrot, ws_vs, ws_vp);
    k_jreg<<<N_J * JSPLIT, 256, 0, stream>>>(Jr, ws_vs, ws_jp);
    k_chain<<<1, 64, 0, stream>>>(ws_jp, ws_R, ws_G);
    k_skin<<<(N_V + 255) / 256, 256, 0, stream>>>(skin_w, ws_G, ws_vp, out);
}

// Round 3
// 138.365 us; speedup vs baseline: 1.2142x; 1.2142x over previous
//
#include <hip/hip_runtime.h>
#include <math.h>

#define N_V 100000
#define N_J 24
#define N_BETAS 300
#define N_POSE 207
#define JSPLIT 25

__constant__ int c_parents[N_J] = {0,0,0,0,1,2,3,4,5,6,7,8,9,9,9,12,13,14,16,17,18,19,20,21};

// ---------------- K1: rodrigues + lrotmin ----------------
__global__ void k_rodrigues(const float* __restrict__ pose,
                            float* __restrict__ ws_R,
                            float* __restrict__ ws_lrot) {
    __shared__ float Rsh[N_J][9];
    int t = threadIdx.x;
    if (t < N_J) {
        float x = pose[t*3+0], y = pose[t*3+1], z = pose[t*3+2];
        float th = sqrtf(x*x + y*y + z*z + 1e-16f);
        float inv = 1.0f / th;
        float rx = x*inv, ry = y*inv, rz = z*inv;
        float c = cosf(th), s = sinf(th), o = 1.0f - c;
        float R[9];
        R[0] = c + o*rx*rx;      R[1] = o*rx*ry - s*rz;  R[2] = o*rx*rz + s*ry;
        R[3] = o*ry*rx + s*rz;   R[4] = c + o*ry*ry;     R[5] = o*ry*rz - s*rx;
        R[6] = o*rz*rx - s*ry;   R[7] = o*rz*ry + s*rx;  R[8] = c + o*rz*rz;
        #pragma unroll
        for (int i = 0; i < 9; ++i) { Rsh[t][i] = R[i]; ws_R[t*9+i] = R[i]; }
    }
    __syncthreads();
    for (int i = t; i < N_POSE; i += blockDim.x) {
        int j = i / 9 + 1, e = i % 9;
        float v = Rsh[j][e];
        if (e == 0 || e == 4 || e == 8) v -= 1.0f;
        ws_lrot[i] = v;
    }
}

// ---------------- K2: block per 4 vertices, wave per vertex ----------------
// vs / vp are SoA: [3][N_V]
__global__ __launch_bounds__(256) void k_vertex(
        const float* __restrict__ shapedirs, const float* __restrict__ posedirs,
        const float* __restrict__ v_template, const float* __restrict__ beta,
        const float* __restrict__ lrot,
        float* __restrict__ vs, float* __restrict__ vp) {
    int lane = threadIdx.x & 63;
    int wave = threadIdx.x >> 6;
    int v = blockIdx.x * 4 + wave;

    // ---- per-wave operands -> registers (L1-resident global reads, no LDS)
    float4 bv[4];
    #pragma unroll
    for (int it = 0; it < 4; ++it) {
        int i = lane + it * 64;                 // float4 index within 225
        int d = (i >= 150) ? 2 : ((i >= 75) ? 1 : 0);
        int k4 = i - d * 75;
        if (it < 3 || i < 225) bv[it] = ((const float4*)beta)[k4];
        else                   bv[it] = make_float4(0.f, 0.f, 0.f, 0.f);
    }
    float lr[10];
    #pragma unroll
    for (int it = 0; it < 10; ++it) {
        int i = lane + it * 64;                 // float index within 621
        int d = (i >= 414) ? 2 : ((i >= 207) ? 1 : 0);
        int p = i - d * 207;
        lr[it] = (it < 9 || i < 621) ? lrot[p] : 0.f;
    }

    const float4* sb = (const float4*)(shapedirs + (size_t)v * 900);
    const float*  pb = posedirs + (size_t)v * 621;

    // ---- issue all loads up front
    float4 s0 = sb[lane];
    float4 s1 = sb[lane + 64];
    float4 s2 = sb[lane + 128];
    float4 s3 = (lane < 33) ? sb[lane + 192] : make_float4(0.f,0.f,0.f,0.f);
    float q0 = pb[lane      ];
    float q1 = pb[lane +  64];
    float q2 = pb[lane + 128];
    float q3 = pb[lane + 192];
    float q4 = pb[lane + 256];
    float q5 = pb[lane + 320];
    float q6 = pb[lane + 384];
    float q7 = pb[lane + 448];
    float q8 = pb[lane + 512];
    float q9 = (lane < 45) ? pb[lane + 576] : 0.f;

    float a0 = 0.f, a1 = 0.f, a2 = 0.f;
    float p0 = 0.f, p1 = 0.f, p2 = 0.f;

    // ---- shapedirs: segment boundaries at float4 index 75 / 150
    float c0 = s0.x*bv[0].x + s0.y*bv[0].y + s0.z*bv[0].z + s0.w*bv[0].w;
    float c1 = s1.x*bv[1].x + s1.y*bv[1].y + s1.z*bv[1].z + s1.w*bv[1].w;
    float c2 = s2.x*bv[2].x + s2.y*bv[2].y + s2.z*bv[2].z + s2.w*bv[2].w;
    float c3 = s3.x*bv[3].x + s3.y*bv[3].y + s3.z*bv[3].z + s3.w*bv[3].w;
    a0 += c0;
    if (lane < 11) a0 += c1; else a1 += c1;     // it1 straddles 75
    if (lane < 22) a1 += c2; else a2 += c2;     // it2 straddles 150
    a2 += c3;                                   // it3 tail, all d2

    // ---- posedirs: boundaries at 207 / 414 / 621
    p0 += q0 * lr[0];
    p0 += q1 * lr[1];
    p0 += q2 * lr[2];
    { float c = q3 * lr[3]; if (lane < 15) p0 += c; else p1 += c; }  // 207
    p1 += q4 * lr[4];
    p1 += q5 * lr[5];
    { float c = q6 * lr[6]; if (lane < 30) p1 += c; else p2 += c; }  // 414
    p2 += q7 * lr[7];
    p2 += q8 * lr[8];
    p2 += q9 * lr[9];                                                // tail

    // ---- 6-value cross-lane reduction
    #pragma unroll
    for (int off = 1; off <= 4; off <<= 1) {
        a0 += __shfl_xor(a0, off); a1 += __shfl_xor(a1, off); a2 += __shfl_xor(a2, off);
        p0 += __shfl_xor(p0, off); p1 += __shfl_xor(p1, off); p2 += __shfl_xor(p2, off);
    }
    int j = lane & 7;
    float val = a0;
    val = (j == 1) ? a1 : val;
    val = (j == 2) ? a2 : val;
    val = (j == 3) ? p0 : val;
    val = (j == 4) ? p1 : val;
    val = (j == 5) ? p2 : val;
    val += __shfl_xor(val, 8);
    val += __shfl_xor(val, 16);
    val += __shfl_xor(val, 32);
    float pj = __shfl(val, lane + 3);   // lane d<3 pulls pose-sum d

    if (lane < 3) {
        float vsd = val + v_template[(size_t)v*3 + lane];
        vs[lane * N_V + v] = vsd;
        vp[lane * N_V + v] = vsd + pj;
    }
}

// ---------------- K3: J partials (float4 over SoA v_shaped) ----------------
__global__ __launch_bounds__(256) void k_jreg(const float* __restrict__ Jr,
                                              const float* __restrict__ vs,
                                              float* __restrict__ jpart) {
    int j = blockIdx.x / JSPLIT;
    int s = blockIdx.x % JSPLIT;
    const int chunk4 = (N_V / JSPLIT) / 4;   // 1000 float4
    int b4 = s * chunk4;
    int t = threadIdx.x;
    const float4* row = (const float4*)(Jr + (size_t)j * N_V);
    const float4* X = (const float4*)(vs);
    const float4* Y = (const float4*)(vs + N_V);
    const float4* Z = (const float4*)(vs + 2 * N_V);
    float a0 = 0.f, a1 = 0.f, a2 = 0.f;
    for (int i = b4 + t; i < b4 + chunk4; i += 256) {
        float4 w = row[i];
        float4 x = X[i], y = Y[i], z = Z[i];
        a0 += w.x*x.x + w.y*x.y + w.z*x.z + w.w*x.w;
        a1 += w.x*y.x + w.y*y.y + w.z*y.z + w.w*y.w;
        a2 += w.x*z.x + w.y*z.y + w.z*z.z + w.w*z.w;
    }
    #pragma unroll
    for (int off = 32; off; off >>= 1) {
        a0 += __shfl_xor(a0, off); a1 += __shfl_xor(a1, off); a2 += __shfl_xor(a2, off);
    }
    __shared__ float red[4][3];
    int wave = t >> 6, lane = t & 63;
    if (lane == 0) { red[wave][0] = a0; red[wave][1] = a1; red[wave][2] = a2; }
    __syncthreads();
    if (t == 0) {
        jpart[(j*JSPLIT+s)*3+0] = red[0][0]+red[1][0]+red[2][0]+red[3][0];
        jpart[(j*JSPLIT+s)*3+1] = red[0][1]+red[1][1]+red[2][1]+red[3][1];
        jpart[(j*JSPLIT+s)*3+2] = red[0][2]+red[1][2]+red[2][2]+red[3][2];
    }
}

// ---------------- K4: reduce J + kinematic chain -> G' [24][12] ------------
__global__ void k_chain(const float* __restrict__ jpart,
                        const float* __restrict__ ws_R,
                        float* __restrict__ ws_G) {
    __shared__ float J[N_J][3];
    __shared__ float G[N_J][16];
    int t = threadIdx.x;   // 64 threads
    for (int i = t; i < N_J * 3; i += 64) {
        int j = i / 3, d = i % 3;
        float s = 0.f;
        for (int k = 0; k < JSPLIT; ++k) s += jpart[(j*JSPLIT+k)*3 + d];
        J[j][d] = s;
    }
    __syncthreads();
    if (t < 16) {
        int a = t / 4, b = t % 4;
        float g;
        if (a < 3) g = (b < 3) ? ws_R[a*3 + b] : J[0][a];
        else       g = (b == 3) ? 1.f : 0.f;
        G[0][t] = g;
    }
    __syncthreads();
    for (int i = 1; i < N_J; ++i) {
        int p = c_parents[i];
        if (t < 16) {
            int a = t / 4, b = t % 4;
            float acc = 0.f;
            #pragma unroll
            for (int k = 0; k < 4; ++k) {
                float Ak;
                if (k < 3) Ak = (b < 3) ? ws_R[i*9 + k*3 + b] : (J[i][k] - J[p][k]);
                else       Ak = (b == 3) ? 1.f : 0.f;
                acc += G[p][a*4 + k] * Ak;
            }
            G[i][t] = acc;
        }
        __syncthreads();
    }
    for (int i = t; i < N_J * 12; i += 64) {
        int j = i / 12, r = i % 12, a = r / 4, b = r % 4;
        float g = G[j][a*4 + b];
        if (b == 3)
            g -= G[j][a*4+0]*J[j][0] + G[j][a*4+1]*J[j][1] + G[j][a*4+2]*J[j][2];
        ws_G[i] = g;
    }
}

// ---------------- K5: skinning (SoA v_posed) --------------------------------
__global__ __launch_bounds__(256) void k_skin(const float* __restrict__ w,
                                              const float* __restrict__ ws_G,
                                              const float* __restrict__ vp,
                                              float* __restrict__ out) {
    __shared__ float G[N_J * 12];
    int t = threadIdx.x;
    for (int i = t; i < N_J * 12; i += 256) G[i] = ws_G[i];
    __syncthreads();
    int v = blockIdx.x * 256 + t;
    if (v >= N_V) return;
    float T[12];
    #pragma unroll
    for (int r = 0; r < 12; ++r) T[r] = 0.f;
    const float4* wv = (const float4*)(w + (size_t)v * 24);
    #pragma unroll
    for (int q = 0; q < 6; ++q) {
        float4 ww = wv[q];
        float wj[4] = {ww.x, ww.y, ww.z, ww.w};
        #pragma unroll
        for (int jj = 0; jj < 4; ++jj) {
            const float* g = &G[(q*4 + jj) * 12];
            #pragma unroll
            for (int r = 0; r < 12; ++r) T[r] += wj[jj] * g[r];
        }
    }
    float px = vp[v], py = vp[N_V + v], pz = vp[2*N_V + v];
    out[v*3+0] = T[0]*px + T[1]*py + T[2]*pz  + T[3];
    out[v*3+1] = T[4]*px + T[5]*py + T[6]*pz  + T[7];
    out[v*3+2] = T[8]*px + T[9]*py + T[10]*pz + T[11];
}

// ---------------- launcher --------------------------------------------------
extern "C" void kernel_launch(void* const* d_in, const int* in_sizes, int n_in,
                              void* d_out, int out_size, void* d_ws, size_t ws_size,
                              hipStream_t stream) {
    const float* beta       = (const float*)d_in[0];
    const float* pose       = (const float*)d_in[1];
    const float* v_template = (const float*)d_in[2];
    const float* Jr         = (const float*)d_in[3];
    const float* skin_w     = (const float*)d_in[4];
    const float* shapedirs  = (const float*)d_in[5];
    const float* posedirs   = (const float*)d_in[6];
    float* out = (float*)d_out;

    float* ws      = (float*)d_ws;
    float* ws_R    = ws;              // 216
    float* ws_lrot = ws + 256;        // 207
    float* ws_vs   = ws + 512;        // 3*N_V  (SoA)
    float* ws_vp   = ws + 512 + 3*N_V;// 3*N_V  (SoA)
    float* ws_jp   = ws + 512 + 6*N_V;           // 24*25*3 = 1800
    float* ws_G    = ws + 512 + 6*N_V + 2048;    // 288

    k_rodrigues<<<1, 256, 0, stream>>>(pose, ws_R, ws_lrot);
    k_vertex<<<N_V / 4, 256, 0, stream>>>(shapedirs, posedirs, v_template,
                                          beta, ws_lrot, ws_vs, ws_vp);
    k_jreg<<<N_J * JSPLIT, 256, 0, stream>>>(Jr, ws_vs, ws_jp);
    k_chain<<<1, 64, 0, stream>>>(ws_jp, ws_R, ws_G);
    k_skin<<<(N_V + 255) / 256, 256, 0, stream>>>(skin_w, ws_G, ws_vp, out);
}

// Round 5
// 130.389 us; speedup vs baseline: 1.2885x; 1.0612x over previous
//
#include <hip/hip_runtime.h>
#include <math.h>

#define N_V 100000
#define N_J 24
#define N_BETAS 300
#define N_POSE 207
#define JSPLIT 25

typedef float f4 __attribute__((ext_vector_type(4)));

__constant__ int c_parents[N_J] = {0,0,0,0,1,2,3,4,5,6,7,8,9,9,9,12,13,14,16,17,18,19,20,21};

// ---------------- K1: rodrigues + lrotmin ----------------
__global__ void k_rodrigues(const float* __restrict__ pose,
                            float* __restrict__ ws_R,
                            float* __restrict__ ws_lrot) {
    __shared__ float Rsh[N_J][9];
    int t = threadIdx.x;
    if (t < N_J) {
        float x = pose[t*3+0], y = pose[t*3+1], z = pose[t*3+2];
        float th = sqrtf(x*x + y*y + z*z + 1e-16f);
        float inv = 1.0f / th;
        float rx = x*inv, ry = y*inv, rz = z*inv;
        float c = cosf(th), s = sinf(th), o = 1.0f - c;
        float R[9];
        R[0] = c + o*rx*rx;      R[1] = o*rx*ry - s*rz;  R[2] = o*rx*rz + s*ry;
        R[3] = o*ry*rx + s*rz;   R[4] = c + o*ry*ry;     R[5] = o*ry*rz - s*rx;
        R[6] = o*rz*rx - s*ry;   R[7] = o*rz*ry + s*rx;  R[8] = c + o*rz*rz;
        #pragma unroll
        for (int i = 0; i < 9; ++i) { Rsh[t][i] = R[i]; ws_R[t*9+i] = R[i]; }
    }
    __syncthreads();
    for (int i = t; i < N_POSE; i += blockDim.x) {
        int j = i / 9 + 1, e = i % 9;
        float v = Rsh[j][e];
        if (e == 0 || e == 4 || e == 8) v -= 1.0f;
        ws_lrot[i] = v;
    }
}

// ---------------- K2: block = 16 contiguous vertices, wave = 4 -------------
// vs / vp are SoA: [3][N_V]
__global__ __launch_bounds__(256) void k_vertex(
        const float* __restrict__ shapedirs, const float* __restrict__ posedirs,
        const float* __restrict__ v_template, const float* __restrict__ beta,
        const float* __restrict__ lrot,
        float* __restrict__ vs, float* __restrict__ vp) {
    int lane = threadIdx.x & 63;
    int wave = threadIdx.x >> 6;
    int vb = blockIdx.x * 16 + wave * 4;    // this wave's 4 vertices

    // ---- per-wave operands -> registers (hoisted, amortized over 4 verts)
    f4 bv[4];
    #pragma unroll
    for (int it = 0; it < 4; ++it) {
        int i = lane + it * 64;                 // float4 index within 225
        int d = (i >= 150) ? 2 : ((i >= 75) ? 1 : 0);
        int k4 = i - d * 75;
        if (it < 3 || i < 225) bv[it] = ((const f4*)beta)[k4];
        else                   bv[it] = (f4){0.f, 0.f, 0.f, 0.f};
    }
    float lr[10];
    #pragma unroll
    for (int it = 0; it < 10; ++it) {
        int i = lane + it * 64;                 // float index within 621
        int d = (i >= 414) ? 2 : ((i >= 207) ? 1 : 0);
        int p = i - d * 207;
        lr[it] = (it < 9 || i < 621) ? lrot[p] : 0.f;
    }

    #pragma unroll 2
    for (int u = 0; u < 4; ++u) {
        int v = vb + u;
        const f4*    sb = (const f4*)(shapedirs + (size_t)v * 900);
        const float* pb = posedirs + (size_t)v * 621;

        // ---- streaming loads (read-once -> nontemporal)
        f4 s0 = __builtin_nontemporal_load(sb + lane);
        f4 s1 = __builtin_nontemporal_load(sb + lane + 64);
        f4 s2 = __builtin_nontemporal_load(sb + lane + 128);
        f4 s3 = (lane < 33) ? __builtin_nontemporal_load(sb + lane + 192)
                            : (f4){0.f, 0.f, 0.f, 0.f};
        float q0 = __builtin_nontemporal_load(pb + lane);
        float q1 = __builtin_nontemporal_load(pb + lane +  64);
        float q2 = __builtin_nontemporal_load(pb + lane + 128);
        float q3 = __builtin_nontemporal_load(pb + lane + 192);
        float q4 = __builtin_nontemporal_load(pb + lane + 256);
        float q5 = __builtin_nontemporal_load(pb + lane + 320);
        float q6 = __builtin_nontemporal_load(pb + lane + 384);
        float q7 = __builtin_nontemporal_load(pb + lane + 448);
        float q8 = __builtin_nontemporal_load(pb + lane + 512);
        float q9 = (lane < 45) ? __builtin_nontemporal_load(pb + lane + 576) : 0.f;

        float a0 = 0.f, a1 = 0.f, a2 = 0.f;
        float p0 = 0.f, p1 = 0.f, p2 = 0.f;

        // ---- shapedirs: segment boundaries at float4 index 75 / 150
        float c0 = s0.x*bv[0].x + s0.y*bv[0].y + s0.z*bv[0].z + s0.w*bv[0].w;
        float c1 = s1.x*bv[1].x + s1.y*bv[1].y + s1.z*bv[1].z + s1.w*bv[1].w;
        float c2 = s2.x*bv[2].x + s2.y*bv[2].y + s2.z*bv[2].z + s2.w*bv[2].w;
        float c3 = s3.x*bv[3].x + s3.y*bv[3].y + s3.z*bv[3].z + s3.w*bv[3].w;
        a0 += c0;
        if (lane < 11) a0 += c1; else a1 += c1;     // it1 straddles 75
        if (lane < 22) a1 += c2; else a2 += c2;     // it2 straddles 150
        a2 += c3;                                   // it3 tail, all d2

        // ---- posedirs: boundaries at 207 / 414 / 621
        p0 += q0 * lr[0];
        p0 += q1 * lr[1];
        p0 += q2 * lr[2];
        { float c = q3 * lr[3]; if (lane < 15) p0 += c; else p1 += c; }  // 207
        p1 += q4 * lr[4];
        p1 += q5 * lr[5];
        { float c = q6 * lr[6]; if (lane < 30) p1 += c; else p2 += c; }  // 414
        p2 += q7 * lr[7];
        p2 += q8 * lr[8];
        p2 += q9 * lr[9];                                                // tail

        // ---- 6-value cross-lane reduction
        #pragma unroll
        for (int off = 1; off <= 4; off <<= 1) {
            a0 += __shfl_xor(a0, off); a1 += __shfl_xor(a1, off); a2 += __shfl_xor(a2, off);
            p0 += __shfl_xor(p0, off); p1 += __shfl_xor(p1, off); p2 += __shfl_xor(p2, off);
        }
        int j = lane & 7;
        float val = a0;
        val = (j == 1) ? a1 : val;
        val = (j == 2) ? a2 : val;
        val = (j == 3) ? p0 : val;
        val = (j == 4) ? p1 : val;
        val = (j == 5) ? p2 : val;
        val += __shfl_xor(val, 8);
        val += __shfl_xor(val, 16);
        val += __shfl_xor(val, 32);
        float pj = __shfl(val, lane + 3);   // lane d<3 pulls pose-sum d

        if (lane < 3) {
            float vsd = val + v_template[(size_t)v*3 + lane];
            vs[lane * N_V + v] = vsd;
            vp[lane * N_V + v] = vsd + pj;
        }
    }
}

// ---------------- K3: J partials (float4 over SoA v_shaped) ----------------
__global__ __launch_bounds__(256) void k_jreg(const float* __restrict__ Jr,
                                              const float* __restrict__ vs,
                                              float* __restrict__ jpart) {
    int j = blockIdx.x / JSPLIT;
    int s = blockIdx.x % JSPLIT;
    const int chunk4 = (N_V / JSPLIT) / 4;   // 1000 float4
    int b4 = s * chunk4;
    int t = threadIdx.x;
    const f4* row = (const f4*)(Jr + (size_t)j * N_V);
    const f4* X = (const f4*)(vs);
    const f4* Y = (const f4*)(vs + N_V);
    const f4* Z = (const f4*)(vs + 2 * N_V);
    float a0 = 0.f, a1 = 0.f, a2 = 0.f;
    for (int i = b4 + t; i < b4 + chunk4; i += 256) {
        f4 w = row[i];
        f4 x = X[i], y = Y[i], z = Z[i];
        a0 += w.x*x.x + w.y*x.y + w.z*x.z + w.w*x.w;
        a1 += w.x*y.x + w.y*y.y + w.z*y.z + w.w*y.w;
        a2 += w.x*z.x + w.y*z.y + w.z*z.z + w.w*z.w;
    }
    #pragma unroll
    for (int off = 32; off; off >>= 1) {
        a0 += __shfl_xor(a0, off); a1 += __shfl_xor(a1, off); a2 += __shfl_xor(a2, off);
    }
    __shared__ float red[4][3];
    int wave = t >> 6, lane = t & 63;
    if (lane == 0) { red[wave][0] = a0; red[wave][1] = a1; red[wave][2] = a2; }
    __syncthreads();
    if (t == 0) {
        jpart[(j*JSPLIT+s)*3+0] = red[0][0]+red[1][0]+red[2][0]+red[3][0];
        jpart[(j*JSPLIT+s)*3+1] = red[0][1]+red[1][1]+red[2][1]+red[3][1];
        jpart[(j*JSPLIT+s)*3+2] = red[0][2]+red[1][2]+red[2][2]+red[3][2];
    }
}

// ---------------- K4: reduce J + kinematic chain -> G' [24][12] ------------
__global__ void k_chain(const float* __restrict__ jpart,
                        const float* __restrict__ ws_R,
                        float* __restrict__ ws_G) {
    __shared__ float J[N_J][3];
    __shared__ float G[N_J][16];
    int t = threadIdx.x;   // 64 threads
    for (int i = t; i < N_J * 3; i += 64) {
        int j = i / 3, d = i % 3;
        float s = 0.f;
        for (int k = 0; k < JSPLIT; ++k) s += jpart[(j*JSPLIT+k)*3 + d];
        J[j][d] = s;
    }
    __syncthreads();
    if (t < 16) {
        int a = t / 4, b = t % 4;
        float g;
        if (a < 3) g = (b < 3) ? ws_R[a*3 + b] : J[0][a];
        else       g = (b == 3) ? 1.f : 0.f;
        G[0][t] = g;
    }
    __syncthreads();
    for (int i = 1; i < N_J; ++i) {
        int p = c_parents[i];
        if (t < 16) {
            int a = t / 4, b = t % 4;
            float acc = 0.f;
            #pragma unroll
            for (int k = 0; k < 4; ++k) {
                float Ak;
                if (k < 3) Ak = (b < 3) ? ws_R[i*9 + k*3 + b] : (J[i][k] - J[p][k]);
                else       Ak = (b == 3) ? 1.f : 0.f;
                acc += G[p][a*4 + k] * Ak;
            }
            G[i][t] = acc;
        }
        __syncthreads();
    }
    for (int i = t; i < N_J * 12; i += 64) {
        int j = i / 12, r = i % 12, a = r / 4, b = r % 4;
        float g = G[j][a*4 + b];
        if (b == 3)
            g -= G[j][a*4+0]*J[j][0] + G[j][a*4+1]*J[j][1] + G[j][a*4+2]*J[j][2];
        ws_G[i] = g;
    }
}

// ---------------- K5: skinning (SoA v_posed) --------------------------------
__global__ __launch_bounds__(256) void k_skin(const float* __restrict__ w,
                                              const float* __restrict__ ws_G,
                                              const float* __restrict__ vp,
                                              float* __restrict__ out) {
    __shared__ float G[N_J * 12];
    int t = threadIdx.x;
    for (int i = t; i < N_J * 12; i += 256) G[i] = ws_G[i];
    __syncthreads();
    int v = blockIdx.x * 256 + t;
    if (v >= N_V) return;
    float T[12];
    #pragma unroll
    for (int r = 0; r < 12; ++r) T[r] = 0.f;
    const f4* wv = (const f4*)(w + (size_t)v * 24);
    #pragma unroll
    for (int q = 0; q < 6; ++q) {
        f4 ww = __builtin_nontemporal_load(wv + q);
        float wj[4] = {ww.x, ww.y, ww.z, ww.w};
        #pragma unroll
        for (int jj = 0; jj < 4; ++jj) {
            const float* g = &G[(q*4 + jj) * 12];
            #pragma unroll
            for (int r = 0; r < 12; ++r) T[r] += wj[jj] * g[r];
        }
    }
    float px = vp[v], py = vp[N_V + v], pz = vp[2*N_V + v];
    out[v*3+0] = T[0]*px + T[1]*py + T[2]*pz  + T[3];
    out[v*3+1] = T[4]*px + T[5]*py + T[6]*pz  + T[7];
    out[v*3+2] = T[8]*px + T[9]*py + T[10]*pz + T[11];
}

// ---------------- launcher --------------------------------------------------
extern "C" void kernel_launch(void* const* d_in, const int* in_sizes, int n_in,
                              void* d_out, int out_size, void* d_ws, size_t ws_size,
                              hipStream_t stream) {
    const float* beta       = (const float*)d_in[0];
    const float* pose       = (const float*)d_in[1];
    const float* v_template = (const float*)d_in[2];
    const float* Jr         = (const float*)d_in[3];
    const float* skin_w     = (const float*)d_in[4];
    const float* shapedirs  = (const float*)d_in[5];
    const float* posedirs   = (const float*)d_in[6];
    float* out = (float*)d_out;

    float* ws      = (float*)d_ws;
    float* ws_R    = ws;              // 216
    float* ws_lrot = ws + 256;        // 207
    float* ws_vs   = ws + 512;        // 3*N_V  (SoA)
    float* ws_vp   = ws + 512 + 3*N_V;// 3*N_V  (SoA)
    float* ws_jp   = ws + 512 + 6*N_V;           // 24*25*3 = 1800
    float* ws_G    = ws + 512 + 6*N_V + 2048;    // 288

    k_rodrigues<<<1, 256, 0, stream>>>(pose, ws_R, ws_lrot);
    k_vertex<<<N_V / 16, 256, 0, stream>>>(shapedirs, posedirs, v_template,
                                           beta, ws_lrot, ws_vs, ws_vp);
    k_jreg<<<N_J * JSPLIT, 256, 0, stream>>>(Jr, ws_vs, ws_jp);
    k_chain<<<1, 64, 0, stream>>>(ws_jp, ws_R, ws_G);
    k_skin<<<(N_V + 255) / 256, 256, 0, stream>>>(skin_w, ws_G, ws_vp, out);
}